// Round 3
// baseline (803.682 us; speedup 1.0000x reference)
//
#include <hip/hip_runtime.h>

#define N_CELLS 8388608
#define N_HALO  1048576
#define STRIDE  16   // floats per cell in packed layout: 64 B = one cache line

typedef float f32x4 __attribute__((ext_vector_type(4)));  // native vec for nontemporal builtins

// Phase 1: streaming transpose+derive, 4 cells per thread.
// fields[12][N_CELLS] row-major -> ws[N_CELLS][16] cell-major (11 derived
// values; the 4th float4 of each line is never written or read).
// Reads: 12 x dwordx4 nontemporal per thread (fully coalesced).
// Writes: 48 B per cell (3 x dwordx4); L2 merges into sector writebacks.
__global__ __launch_bounds__(256) void pack_kernel(
    const float* __restrict__ fields, float* __restrict__ ws)
{
    const size_t t  = blockIdx.x * blockDim.x + threadIdx.x;  // one thread = 4 cells
    const size_t c4 = t * 4;
    if (c4 >= N_CELLS) return;

    // f[q] = 4 consecutive cells of fields row q
    f32x4 f[12];
    #pragma unroll
    for (int q = 0; q < 12; ++q)
        f[q] = __builtin_nontemporal_load(
            reinterpret_cast<const f32x4*>(fields + (size_t)q * N_CELLS + c4));

    #pragma unroll
    for (int j = 0; j < 4; ++j) {
        // fields rows: 0:u 1:v 2:b_u 3:b_v 4:h 5:Hb 6:hh 7:dif_h 8:eta1 9:k_u 10:k_v 11:k3
        const float u    = f[0][j],  v    = f[1][j];
        const float bu   = f[2][j],  bv   = f[3][j];
        const float h    = f[4][j],  Hb   = f[5][j];
        const float hh   = f[6][j],  difh = f[7][j];
        const float eta1 = f[8][j];
        const float ku   = f[9][j],  kv   = f[10][j], k3 = f[11][j];

        f32x4* o = reinterpret_cast<f32x4*>(ws + (c4 + j) * STRIDE);
        // derived order: 0:u 1:v 2:b_u 3:b_v 4:h 5:hh 6:dif_h 7:h+Hb 8:eta1 9:min(ku,k3) 10:min(kv,k3)
        o[0] = (f32x4){u, v, bu, bv};
        o[1] = (f32x4){h, hh, difh, h + Hb};
        o[2] = (f32x4){eta1, fminf(ku, k3), fminf(kv, k3), 0.0f};
        // o[3] intentionally not written (never read)
    }
}

// Phase 2: per halo element, gather one 64-B line per source cell
// (3 x dwordx4 = the only random fetches: ~1.5M lines total), blend,
// store q-major coalesced.
__global__ __launch_bounds__(256) void gather_kernel(
    const float* __restrict__ ws, const int2* __restrict__ src_idx,
    const float2* __restrict__ weights, float* __restrict__ out)
{
    const int e = blockIdx.x * blockDim.x + threadIdx.x;
    if (e >= N_HALO) return;

    const int2   ij = src_idx[e];
    const float2 wv = weights[e];

    const f32x4* p0 = reinterpret_cast<const f32x4*>(ws + (size_t)ij.x * STRIDE);
    f32x4 a0 = p0[0], a1 = p0[1], a2 = p0[2];

    f32x4 b0 = (f32x4){0, 0, 0, 0}, b1 = b0, b2 = b0;
    if (wv.y != 0.0f) {  // ~50% of elements have no second source
        const f32x4* p1 = reinterpret_cast<const f32x4*>(ws + (size_t)ij.y * STRIDE);
        b0 = p1[0]; b1 = p1[1]; b2 = p1[2];
    }

    const float w0 = wv.x, w1 = wv.y;
    out[0ull*N_HALO + e]  = a0[0]*w0 + b0[0]*w1;  // u
    out[1ull*N_HALO + e]  = a0[1]*w0 + b0[1]*w1;  // v
    out[2ull*N_HALO + e]  = a0[2]*w0 + b0[2]*w1;  // b_u
    out[3ull*N_HALO + e]  = a0[3]*w0 + b0[3]*w1;  // b_v
    out[4ull*N_HALO + e]  = a1[0]*w0 + b1[0]*w1;  // h
    out[5ull*N_HALO + e]  = a1[1]*w0 + b1[1]*w1;  // hh
    out[6ull*N_HALO + e]  = a1[2]*w0 + b1[2]*w1;  // dif_h
    out[7ull*N_HALO + e]  = a1[3]*w0 + b1[3]*w1;  // h+Hb
    out[8ull*N_HALO + e]  = a2[0]*w0 + b2[0]*w1;  // eta1
    out[9ull*N_HALO + e]  = a2[1]*w0 + b2[1]*w1;  // min(k_u,k3)
    out[10ull*N_HALO + e] = a2[2]*w0 + b2[2]*w1;  // min(k_v,k3)
}

extern "C" void kernel_launch(void* const* d_in, const int* in_sizes, int n_in,
                              void* d_out, int out_size, void* d_ws, size_t ws_size,
                              hipStream_t stream) {
    const float*  fields  = (const float*)d_in[0];
    const int2*   src_idx = (const int2*)d_in[1];
    const float2* weights = (const float2*)d_in[2];
    float* out = (float*)d_out;
    float* ws  = (float*)d_ws;  // needs N_CELLS*16*4 = 512 MB

    const int block = 256;
    const int cells_per_block = block * 4;
    pack_kernel  <<<(N_CELLS + cells_per_block - 1) / cells_per_block, block, 0, stream>>>(fields, ws);
    gather_kernel<<<(N_HALO + block - 1) / block, block, 0, stream>>>(ws, src_idx, weights, out);
}